// Round 2
// baseline (1526.072 us; speedup 1.0000x reference)
//
#include <hip/hip_runtime.h>

// ---------------------------------------------------------------------------
// SAM windowed-attention block, bf16-MFMA implementation.
// B=8 H=W=64 DIM=768 NH=12 HD=64 WS=14 N=196 PAD=6 -> 70x70, 5x5=25 windows,
// Bp=200 windows, 2400 (window,head) pairs. All GEMMs bf16 MFMA 16x16x32,
// fp32 accumulate. Softmax/LN/gelu in fp32.
// R2: GEMM rewritten as 256x256 8-phase pipelined kernel (learn_hip m201
// template): 512 thr / 8 waves (2x4), BK=64, 128KiB LDS dbuf, per-phase
// half-tile global_load_lds staging with counted vmcnt(4) (no drain-to-0 in
// steady state), XOR bank swizzle (linear DMA dest + inverse-swizzled global
// source + swizzled ds_read), s_setprio(1) around MFMA clusters.
// ---------------------------------------------------------------------------

typedef __bf16 bf16x8 __attribute__((ext_vector_type(8)));
typedef float f32x4 __attribute__((ext_vector_type(4)));
typedef unsigned int u32x4 __attribute__((ext_vector_type(4)));

__device__ __forceinline__ unsigned short f2bf(float f) {
  unsigned int u = __builtin_bit_cast(unsigned int, f);
  u += 0x7FFFu + ((u >> 16) & 1u);
  return (unsigned short)(u >> 16);
}

__device__ __forceinline__ bf16x8 ld8(const unsigned short* p) {
  return __builtin_bit_cast(bf16x8, *(const u32x4*)p);
}

// async global->LDS, 16B per lane. LDS dest must be wave-uniform base + lane*16.
__device__ __forceinline__ void gload_lds16(const unsigned short* g,
                                            unsigned short* l) {
  __builtin_amdgcn_global_load_lds(
      (const __attribute__((address_space(1))) unsigned int*)g,
      (__attribute__((address_space(3))) unsigned int*)l, 16, 0, 0);
}

// ---------------------------------------------------------------------------
// Weight transpose fp32[K][N] -> bf16[N][K]  (all dims multiples of 32)
// ---------------------------------------------------------------------------
__global__ void transpose_w(const float* __restrict__ in,
                            unsigned short* __restrict__ out, int K, int N) {
  __shared__ float t[32][33];
  int n = blockIdx.x * 32 + threadIdx.x;
  int kb = blockIdx.y * 32;
#pragma unroll
  for (int i = 0; i < 4; i++) {
    int k = kb + threadIdx.y + i * 8;
    t[threadIdx.y + i * 8][threadIdx.x] = in[(size_t)k * N + n];
  }
  __syncthreads();
  int k2 = kb + threadIdx.x;
#pragma unroll
  for (int i = 0; i < 4; i++) {
    int n2 = blockIdx.x * 32 + threadIdx.y + i * 8;
    out[(size_t)n2 * K + k2] = f2bf(t[threadIdx.x][threadIdx.y + i * 8]);
  }
}

// ---------------------------------------------------------------------------
// Rel-pos tables: Sh[i*14+j] = sum_c rel_h[(i-j+13)*64+c]; same for Sw.
// out layout: [0..195]=Sh, [196..391]=Sw
// ---------------------------------------------------------------------------
__global__ void shsw_kernel(const float* __restrict__ rh,
                            const float* __restrict__ rw,
                            float* __restrict__ o) {
  int t = threadIdx.x;
  if (t < 196) {
    int i = t / 14, j = t % 14, d = i - j + 13;
    float sh = 0.f, sw = 0.f;
    for (int c = 0; c < 64; c++) {
      sh += rh[d * 64 + c];
      sw += rw[d * 64 + c];
    }
    o[t] = sh;
    o[196 + t] = sw;
  }
}

// ---------------------------------------------------------------------------
// LayerNorm over 768. windowed=1: write to window-partitioned layout
// [win*196+t][768]; windowed=0: write [row][768]. Output bf16.
// ---------------------------------------------------------------------------
__global__ __launch_bounds__(256) void ln_kernel(
    const float* __restrict__ xin, const float* __restrict__ w,
    const float* __restrict__ b, unsigned short* __restrict__ out,
    int windowed) {
  __shared__ float red[8];
  __shared__ float ms[2];
  const int tid = threadIdx.x;
  const int blk = blockIdx.x;
  const float* xr = xin + (size_t)blk * 768;
  float v0 = xr[tid], v1 = xr[tid + 256], v2 = xr[tid + 512];
  float s = v0 + v1 + v2;
  float q = v0 * v0 + v1 * v1 + v2 * v2;
#pragma unroll
  for (int off = 32; off > 0; off >>= 1) {
    s += __shfl_down(s, off, 64);
    q += __shfl_down(q, off, 64);
  }
  const int wv = tid >> 6, lane = tid & 63;
  if (lane == 0) { red[wv] = s; red[4 + wv] = q; }
  __syncthreads();
  if (tid == 0) {
    float st = red[0] + red[1] + red[2] + red[3];
    float qt = red[4] + red[5] + red[6] + red[7];
    float mu = st * (1.0f / 768.0f);
    float var = qt * (1.0f / 768.0f) - mu * mu;
    ms[0] = mu;
    ms[1] = rsqrtf(var + 1e-5f);
  }
  __syncthreads();
  float mu = ms[0], sc = ms[1];
  unsigned short* dst;
  if (windowed) {
    int bb = blk >> 12, rem = blk & 4095, h = rem >> 6, ww = rem & 63;
    int win = (bb * 5 + h / 14) * 5 + ww / 14;
    int t = (h % 14) * 14 + (ww % 14);
    dst = out + ((size_t)win * 196 + t) * 768;
  } else {
    dst = out + (size_t)blk * 768;
  }
  dst[tid] = f2bf((v0 - mu) * sc * w[tid] + b[tid]);
  dst[tid + 256] = f2bf((v1 - mu) * sc * w[tid + 256] + b[tid + 256]);
  dst[tid + 512] = f2bf((v2 - mu) * sc * w[tid + 512] + b[tid + 512]);
}

// ---------------------------------------------------------------------------
// bf16 GEMM: C[M][N] = A[M][K] @ Bt[N][K]^T (+ epilogue)
// 256x256 tile, BK=64, 512 threads = 8 waves (2M x 4N), per-wave 128x64 out
// (acc[8][4] f32x4). LDS: 2 buffers x (A 32KB + B 32KB) = 128KB.
// Tile t lives in buf[t&1]. Per tile, 4 phases (one 64x32 quadrant x K=64):
//   ph1: ds_read A-lo+B-lo frags | stage B-hi(t+1) | bar | MFMA(rlo,clo) | bar
//   ph2: ds_read B-hi frags      | stage A-hi(t+1) | bar | MFMA(rlo,chi) | bar
//   ph3: ds_read A-hi frags      | stage B-lo(t+2) | bar | MFMA(rhi,clo) | bar
//   ph4: (regs only)             | stage A-lo(t+2) | vmcnt(4) | bar | MFMA | bar
// Staged halves overwrite regions provably dead >=1 barrier earlier; the
// single vmcnt(4)/tile covers full residency of tile t+1 (2 half-tiles = 4
// loads stay in flight across barriers -- no drain-to-0 in the main loop).
// Bank swizzle: LDS slot = chunk ^ (row&7); DMA dest stays linear, the global
// SOURCE is inverse-permuted, ds_read applies the same XOR (rule #21).
// EPI: 0=+bias->bf16 (qkv), 1=+bias+resid, window-unpartition ->fp32 d_out
//      2=+bias,gelu->bf16 (mlp1), 3=+bias, d_out += (mlp2)
// ---------------------------------------------------------------------------
template <int EPI>
__global__ __launch_bounds__(512, 2) void gemm_bt(
    const unsigned short* __restrict__ A, const unsigned short* __restrict__ Bt,
    const float* __restrict__ bias, int M, int N, int K,
    unsigned short* __restrict__ obf, float* __restrict__ of,
    const float* __restrict__ resid) {
  __shared__ __align__(16) unsigned short smem[65536];  // 128 KiB

  const int tid = threadIdx.x;
  const int lane = tid & 63, wv = tid >> 6;
  const int ln15 = lane & 15, quad = lane >> 4;
  const int wm = wv & 1, wn = wv >> 1;  // 2 x 4 wave grid

  // bijective XCD-chunked swizzle (8 XCDs)
  int bid = blockIdx.y * gridDim.x + blockIdx.x;
  {
    const int nwg = gridDim.x * gridDim.y;
    const int qq = nwg >> 3, rr = nwg & 7;
    const int xcd = bid & 7, lo = bid >> 3;
    bid = (xcd < rr ? xcd * (qq + 1) : rr * (qq + 1) + (xcd - rr) * qq) + lo;
  }
  const int m0 = (bid / gridDim.x) * 256, n0 = (bid % gridDim.x) * 256;

  // ---- staging geometry: thread covers LDS slots s=tid and s=512+tid of a
  // 1024-slot (128 rows x 8 chunks) half-tile. Content of slot (r,sl) is
  // global chunk sl ^ (r&7); since rows for q=0/1 differ by 64, the source
  // chunk offset is the same for both. ----
  const int r0 = tid >> 3;
  const int cOff = ((tid & 7) ^ (r0 & 7)) * 8;
  int rA[4];
#pragma unroll
  for (int hq = 0; hq < 4; hq++) rA[hq] = min(m0 + hq * 64 + r0, M - 1);
  const unsigned short* pB = Bt + (size_t)(n0 + r0) * K + cOff;

  // ds_read swizzled chunk offsets for the two 32-wide k-slices
  int chnk[2];
#pragma unroll
  for (int ks = 0; ks < 2; ks++) chnk[ks] = ((ks * 4 + quad) ^ (ln15 & 7)) * 8;

  const f32x4 fz = {0.f, 0.f, 0.f, 0.f};
  f32x4 acc[8][4];
#pragma unroll
  for (int i = 0; i < 8; i++)
#pragma unroll
    for (int j = 0; j < 4; j++) acc[i][j] = fz;

  bf16x8 af[4][2];       // current A row-quadrant frags [fi][ks]
  bf16x8 bf_[2][2][2];   // B frags [ch][fj][ks], both col-halves held

#define STAGE_A(BB, HH, KT)                                                   \
  do {                                                                        \
    unsigned short* d_ = smem + (BB)*32768 + (HH)*8192 + tid * 8;             \
    gload_lds16(A + (size_t)rA[(HH)*2 + 0] * K + cOff + (KT), d_);            \
    gload_lds16(A + (size_t)rA[(HH)*2 + 1] * K + cOff + (KT), d_ + 4096);     \
  } while (0)
#define STAGE_B(BB, HH, KT)                                                   \
  do {                                                                        \
    unsigned short* d_ = smem + (BB)*32768 + 16384 + (HH)*8192 + tid * 8;     \
    gload_lds16(pB + (size_t)((HH)*128) * K + (KT), d_);                      \
    gload_lds16(pB + (size_t)((HH)*128 + 64) * K + (KT), d_ + 4096);          \
  } while (0)
#define LOAD_A(BB, QRH)                                                       \
  do {                                                                        \
    const unsigned short* ab_ = smem + (BB)*32768 + wm * 8192;                \
    _Pragma("unroll") for (int fi = 0; fi < 4; fi++)                          \
        _Pragma("unroll") for (int ks = 0; ks < 2; ks++)                      \
            af[fi][ks] =                                                      \
        ld8(ab_ + ((QRH)*64 + fi * 16 + ln15) * 64 + chnk[ks]);               \
  } while (0)
#define LOAD_B(BB, CH)                                                        \
  do {                                                                        \
    const unsigned short* bb_ =                                               \
        smem + (BB)*32768 + 16384 + (wn >> 1) * 8192 + (wn & 1) * 4096;       \
    _Pragma("unroll") for (int fj = 0; fj < 2; fj++)                          \
        _Pragma("unroll") for (int ks = 0; ks < 2; ks++)                      \
            bf_[CH][fj][ks] =                                                 \
        ld8(bb_ + ((CH)*32 + fj * 16 + ln15) * 64 + chnk[ks]);                \
  } while (0)
#define MFMA16(QRH, CH)                                                       \
  do {                                                                        \
    _Pragma("unroll") for (int fi = 0; fi < 4; fi++)                          \
        _Pragma("unroll") for (int fj = 0; fj < 2; fj++)                      \
            _Pragma("unroll") for (int ks = 0; ks < 2; ks++)                  \
                acc[(QRH)*4 + fi][(CH)*2 + fj] =                              \
        __builtin_amdgcn_mfma_f32_16x16x32_bf16(                              \
            af[fi][ks], bf_[CH][fj][ks], acc[(QRH)*4 + fi][(CH)*2 + fj], 0,   \
            0, 0);                                                            \
  } while (0)
#define BAR() __builtin_amdgcn_s_barrier()
#define PRIO1 __builtin_amdgcn_s_setprio(1)
#define PRIO0 __builtin_amdgcn_s_setprio(0)

  // TILE: one K-tile in buffer BB (next buffer NB). S12: stage hi-halves of
  // tile t+1 (global k = KT1). S34: stage lo-halves of t+2 (k = KT2).
  // W: 0 -> vmcnt(4) steady, 1 -> vmcnt(0) tail drain, 2 -> none.
#define TILE(BB, NB, KT1, KT2, S12, S34, W)                                   \
  do {                                                                        \
    LOAD_A(BB, 0);                                                            \
    LOAD_B(BB, 0);                                                            \
    if (S12) STAGE_B(NB, 1, KT1);                                             \
    BAR(); PRIO1; MFMA16(0, 0); PRIO0; BAR();                                 \
    LOAD_B(BB, 1);                                                            \
    if (S12) STAGE_A(NB, 1, KT1);                                             \
    BAR(); PRIO1; MFMA16(0, 1); PRIO0; BAR();                                 \
    LOAD_A(BB, 1);                                                            \
    if (S34) STAGE_B(BB, 0, KT2);                                             \
    BAR(); PRIO1; MFMA16(1, 0); PRIO0; BAR();                                 \
    if (S34) STAGE_A(BB, 0, KT2);                                             \
    if ((W) == 0) {                                                           \
      asm volatile("s_waitcnt vmcnt(4)" ::: "memory");                        \
      __builtin_amdgcn_sched_barrier(0);                                      \
    } else if ((W) == 1) {                                                    \
      asm volatile("s_waitcnt vmcnt(0)" ::: "memory");                        \
      __builtin_amdgcn_sched_barrier(0);                                      \
    }                                                                         \
    BAR(); PRIO1; MFMA16(1, 1); PRIO0; BAR();                                 \
  } while (0)

  const int NT = K >> 6;  // 12 or 48, even, >= 4

  // prologue: tile0 fully + tile1 lo-halves, in steady-state relative order
  STAGE_B(0, 0, 0);
  STAGE_A(0, 0, 0);
  STAGE_B(0, 1, 0);
  STAGE_A(0, 1, 0);
  STAGE_B(1, 0, 64);
  STAGE_A(1, 0, 64);
  asm volatile("s_waitcnt vmcnt(4)" ::: "memory");
  __builtin_amdgcn_sched_barrier(0);
  BAR();

  int kt = 0;
  for (int t = 0; t + 3 < NT; t += 2) {
    TILE(0, 1, kt + 64, kt + 128, 1, 1, 0);
    TILE(1, 0, kt + 128, kt + 192, 1, 1, 0);
    kt += 128;
  }
  // tile NT-2 (b=0): stage hi-halves of NT-1, then drain
  TILE(0, 1, kt + 64, 0, 1, 0, 1);
  // tile NT-1 (b=1): everything resident, nothing left in flight
  TILE(1, 0, 0, 0, 0, 0, 2);

#undef TILE
#undef STAGE_A
#undef STAGE_B
#undef LOAD_A
#undef LOAD_B
#undef MFMA16
#undef BAR
#undef PRIO1
#undef PRIO0

  // Epilogue. C/D layout: col = lane&15, row = quad*4 + reg (verified m89/m91).
#pragma unroll
  for (int i = 0; i < 8; i++) {
#pragma unroll
    for (int j = 0; j < 4; j++) {
      const int col = n0 + wn * 64 + j * 16 + ln15;
      const float bc = bias[col];
#pragma unroll
      for (int g = 0; g < 4; g++) {
        const int row = m0 + wm * 128 + i * 16 + quad * 4 + g;
        if (row >= M) continue;
        float v = acc[i][j][g] + bc;
        if constexpr (EPI == 0) {
          obf[(size_t)row * N + col] = f2bf(v);
        } else if constexpr (EPI == 2) {
          float gl = 0.5f * v * (1.0f + erff(v * 0.70710678118f));
          obf[(size_t)row * N + col] = f2bf(gl);
        } else if constexpr (EPI == 1) {
          // row -> (b,h,w) via window unpartition; drop padded positions
          int win = row / 196, t = row - win * 196;
          int b = win / 25, wg = win - b * 25;
          int wr = wg / 5, wc = wg - wr * 5;
          int h = wr * 14 + t / 14;
          int w = wc * 14 + (t % 14);
          if (h < 64 && w < 64) {
            size_t oi = (((size_t)(b * 64 + h)) * 64 + w) * 768 + col;
            of[oi] = v + resid[oi];
          }
        } else {  // EPI == 3
          size_t oi = (size_t)row * N + col;
          of[oi] += v;
        }
      }
    }
  }
}

// ---------------------------------------------------------------------------
// Fused windowed attention: one block per (window, head). 2400 blocks.
// qkv: bf16 [200*196][2304]; q cols h*64.., k cols 768+h*64.., v 1536+h*64..
// S = (Q Kt)*0.125 + Sh[qr,kr] + Sw[qc,kc]; softmax; O = P V.
// Q/K fragments read directly from global (L1-resident); V transposed in LDS;
// P strip round-trips LDS per wave (C-layout -> A-layout).
// ---------------------------------------------------------------------------
__global__ __launch_bounds__(256, 2) void attn_kernel(
    const unsigned short* __restrict__ qkv, const int* __restrict__ q_idx,
    const int* __restrict__ k_idx, const float* __restrict__ shsw,
    unsigned short* __restrict__ attnout) {
  __shared__ __align__(16) unsigned short Vt[64][232];   // [channel][key] pad->2-way banks
  __shared__ __align__(16) unsigned short Pst[4][16 * 232];  // per-wave P strip
  __shared__ float Shs[196], Sws[196];
  __shared__ short qr14a[208], qc14a[208], kra[208], kca[208];

  const int tid = threadIdx.x;
  const int blk = blockIdx.x;
  const int win = blk / 12, head = blk % 12;
  const int lane = tid & 63, wv = tid >> 6;
  const int ln15 = lane & 15, quad = lane >> 4;
  const unsigned short* qg = qkv + (size_t)win * 196 * 2304;

  // zero Vt & Pst (covers key/col padding 196..223 and strip cols 208..223)
  {
    unsigned int* vz = (unsigned int*)&Vt[0][0];
    for (int i = tid; i < 64 * 232 / 2; i += 256) vz[i] = 0u;
    unsigned int* pz = (unsigned int*)&Pst[0][0];
    for (int i = tid; i < 4 * 16 * 232 / 2; i += 256) pz[i] = 0u;
  }
  // V -> Vt transposed
  for (int i = tid; i < 196 * 64; i += 256) {
    int r = i >> 6, c = i & 63;
    Vt[c][r] = qg[(size_t)r * 2304 + 1536 + head * 64 + c];
  }
  // bias tables + index arrays
  for (int i = tid; i < 208; i += 256) {
    if (i < 196) {
      Shs[i] = shsw[i];
      Sws[i] = shsw[196 + i];
    }
    int q = (i < 196) ? q_idx[(size_t)blk * 196 + i] : 0;
    int k = (i < 196) ? k_idx[(size_t)blk * 196 + i] : 0;
    qr14a[i] = (short)((q / 14) * 14);
    qc14a[i] = (short)((q % 14) * 14);
    kra[i] = (short)(k / 14);
    kca[i] = (short)(k % 14);
  }
  __syncthreads();

  const f32x4 fz = {0.f, 0.f, 0.f, 0.f};
  unsigned short* strip = &Pst[wv][0];

  for (int mt = wv; mt < 13; mt += 4) {
    // ---- Q fragments (A-layout: m=lane&15, k=quad*8+j) from global ----
    int qrow = mt * 16 + ln15;
    int qrc = (qrow < 196) ? qrow : 0;
    const unsigned short* qrp = qg + (size_t)qrc * 2304 + head * 64 + quad * 8;
    bf16x8 aq0 = ld8(qrp);
    bf16x8 aq1 = ld8(qrp + 32);

    // ---- S = Q K^T over 13 col tiles ----
    f32x4 sacc[13];
#pragma unroll
    for (int nt = 0; nt < 13; nt++) {
      sacc[nt] = fz;
      int krow = nt * 16 + ln15;
      if (krow > 195) krow = 0;
      const unsigned short* krp =
          qg + (size_t)krow * 2304 + 768 + head * 64 + quad * 8;
      bf16x8 bk0 = ld8(krp);
      bf16x8 bk1 = ld8(krp + 32);
      sacc[nt] = __builtin_amdgcn_mfma_f32_16x16x32_bf16(aq0, bk0, sacc[nt], 0, 0, 0);
      sacc[nt] = __builtin_amdgcn_mfma_f32_16x16x32_bf16(aq1, bk1, sacc[nt], 0, 0, 0);
    }

    // ---- softmax (rows = quad*4+g of this mt tile) ----
    const int r0 = mt * 16 + quad * 4;
    int qi[4], qci[4];
#pragma unroll
    for (int g = 0; g < 4; g++) {
      qi[g] = qr14a[r0 + g];
      qci[g] = qc14a[r0 + g];
    }
    float rmax[4] = {-1e30f, -1e30f, -1e30f, -1e30f};
#pragma unroll
    for (int nt = 0; nt < 13; nt++) {
      int col = nt * 16 + ln15;
      int kr_ = kra[col], kc_ = kca[col];
#pragma unroll
      for (int g = 0; g < 4; g++) {
        float v = sacc[nt][g] * 0.125f + Shs[qi[g] + kr_] + Sws[qci[g] + kc_];
        if (col >= 196) v = -1e30f;
        sacc[nt][g] = v;
        rmax[g] = fmaxf(rmax[g], v);
      }
    }
#pragma unroll
    for (int off = 1; off < 16; off <<= 1)
#pragma unroll
      for (int g = 0; g < 4; g++)
        rmax[g] = fmaxf(rmax[g], __shfl_xor(rmax[g], off, 16));
    float rsum[4] = {0.f, 0.f, 0.f, 0.f};
#pragma unroll
    for (int nt = 0; nt < 13; nt++) {
      int col = nt * 16 + ln15;
#pragma unroll
      for (int g = 0; g < 4; g++) {
        float p = (col >= 196) ? 0.f : __expf(sacc[nt][g] - rmax[g]);
        sacc[nt][g] = p;
        rsum[g] += p;
      }
    }
#pragma unroll
    for (int off = 1; off < 16; off <<= 1)
#pragma unroll
      for (int g = 0; g < 4; g++) rsum[g] += __shfl_xor(rsum[g], off, 16);
    float rinv[4];
#pragma unroll
    for (int g = 0; g < 4; g++) rinv[g] = 1.0f / rsum[g];

    // ---- write P strip (row-major [16][232] bf16, A-layout source for PV) ----
#pragma unroll
    for (int nt = 0; nt < 13; nt++) {
      int col = nt * 16 + ln15;
#pragma unroll
      for (int g = 0; g < 4; g++)
        strip[(quad * 4 + g) * 232 + col] = f2bf(sacc[nt][g] * rinv[g]);
    }

    // ---- O = P V  (K padded to 224; strip/Vt zeros beyond 196) ----
    f32x4 oacc[4];
#pragma unroll
    for (int c4 = 0; c4 < 4; c4++) oacc[c4] = fz;
#pragma unroll
    for (int ks = 0; ks < 7; ks++) {
      bf16x8 ap = ld8(strip + ln15 * 232 + ks * 32 + quad * 8);
#pragma unroll
      for (int c4 = 0; c4 < 4; c4++) {
        bf16x8 bvv = ld8(&Vt[c4 * 16 + ln15][ks * 32 + quad * 8]);
        oacc[c4] = __builtin_amdgcn_mfma_f32_16x16x32_bf16(ap, bvv, oacc[c4], 0, 0, 0);
      }
    }
    // ---- store (C-layout: col=lane&15 channel, row=quad*4+g token) ----
#pragma unroll
    for (int c4 = 0; c4 < 4; c4++)
#pragma unroll
      for (int g = 0; g < 4; g++) {
        int row = r0 + g;
        if (row < 196)
          attnout[((size_t)win * 196 + row) * 768 + head * 64 + c4 * 16 + ln15] =
              f2bf(oacc[c4][g]);
      }
  }
}

// ---------------------------------------------------------------------------
// Launch. Workspace layout (bytes):
//   [0, 60211200)              region A: xw bf16 [39200][768] -> attnout -> ln2
//   [60211200, 261537792)      region B: qkv bf16 [39200][2304] -> mlp1 [32768][3072]
//   [261537792, ...)           transposed weights bf16 + ShSw tables (~14.2 MB)
// Peak ws use ~276 MB.
// ---------------------------------------------------------------------------
extern "C" void kernel_launch(void* const* d_in, const int* in_sizes, int n_in,
                              void* d_out, int out_size, void* d_ws,
                              size_t ws_size, hipStream_t stream) {
  const float* x = (const float*)d_in[0];
  const int* q_idx = (const int*)d_in[1];
  const int* k_idx = (const int*)d_in[2];
  const float* ln1w = (const float*)d_in[3];
  const float* ln1b = (const float*)d_in[4];
  const float* ln2w = (const float*)d_in[5];
  const float* ln2b = (const float*)d_in[6];
  const float* qkvw = (const float*)d_in[7];
  const float* qkvb = (const float*)d_in[8];
  const float* projw = (const float*)d_in[9];
  const float* projb = (const float*)d_in[10];
  const float* relh = (const float*)d_in[11];
  const float* relw = (const float*)d_in[12];
  const float* w1 = (const float*)d_in[13];
  const float* b1 = (const float*)d_in[14];
  const float* w2 = (const float*)d_in[15];
  const float* b2 = (const float*)d_in[16];
  float* out = (float*)d_out;

  char* ws = (char*)d_ws;
  unsigned short* xw = (unsigned short*)ws;  // region A
  const size_t offA = 60211200;              // 39200*768*2
  unsigned short* qkv = (unsigned short*)(ws + offA);  // region B
  const size_t offB = offA + 201326592;      // max(qkv, mlp1)
  unsigned short* qkvwt = (unsigned short*)(ws + offB);
  unsigned short* projwt = qkvwt + 2304 * 768;
  unsigned short* w1t = projwt + 768 * 768;
  unsigned short* w2t = w1t + 3072 * 768;
  float* shsw = (float*)(w2t + 768 * 3072);

  unsigned short* attnout = xw;  // region A reuse (xw dead after qkv GEMM)
  unsigned short* ln2buf = xw;   // region A reuse (attnout dead after proj)
  unsigned short* mlp1 = qkv;    // region B reuse (qkv dead after attention)

  // zero xw so spatially-padded window tokens are zero feature vectors
  hipMemsetAsync(xw, 0, (size_t)39200 * 768 * 2, stream);

  dim3 tb(32, 8);
  transpose_w<<<dim3(2304 / 32, 768 / 32), tb, 0, stream>>>(qkvw, qkvwt, 768, 2304);
  transpose_w<<<dim3(768 / 32, 768 / 32), tb, 0, stream>>>(projw, projwt, 768, 768);
  transpose_w<<<dim3(3072 / 32, 768 / 32), tb, 0, stream>>>(w1, w1t, 768, 3072);
  transpose_w<<<dim3(768 / 32, 3072 / 32), tb, 0, stream>>>(w2, w2t, 3072, 768);
  shsw_kernel<<<1, 256, 0, stream>>>(relh, relw, shsw);

  // LN1 + window partition -> bf16
  ln_kernel<<<32768, 256, 0, stream>>>(x, ln1w, ln1b, xw, 1);

  // qkv = xw @ qkv_w + b   [39200,768]x[768,2304]  (154x9 tiles of 256)
  gemm_bt<0><<<dim3(9, 154), 512, 0, stream>>>(xw, qkvwt, qkvb, 39200, 2304,
                                               768, qkv, nullptr, nullptr);
  // fused windowed attention
  attn_kernel<<<2400, 256, 0, stream>>>(qkv, q_idx, k_idx, shsw, attnout);

  // proj + residual + unpartition -> d_out (fp32 x_mid)
  gemm_bt<1><<<dim3(3, 154), 512, 0, stream>>>(attnout, projwt, projb, 39200,
                                               768, 768, nullptr, out, x);
  // LN2 -> bf16
  ln_kernel<<<32768, 256, 0, stream>>>(out, ln2w, ln2b, ln2buf, 0);

  // mlp1 = gelu(ln2 @ w1 + b1)   [32768,768]x[768,3072]
  gemm_bt<2><<<dim3(12, 128), 512, 0, stream>>>(ln2buf, w1t, b1, 32768, 3072,
                                                768, mlp1, nullptr, nullptr);
  // d_out += mlp1 @ w2 + b2      [32768,3072]x[3072,768]
  gemm_bt<3><<<dim3(3, 128), 512, 0, stream>>>(mlp1, w2t, b2, 32768, 768, 3072,
                                               nullptr, out, nullptr);
  (void)in_sizes; (void)n_in; (void)out_size; (void)ws_size;
}

// Round 3
// 1283.629 us; speedup vs baseline: 1.1889x; 1.1889x over previous
//
#include <hip/hip_runtime.h>

// ---------------------------------------------------------------------------
// SAM windowed-attention block, bf16-MFMA implementation.
// B=8 H=W=64 DIM=768 NH=12 HD=64 WS=14 N=196 PAD=6 -> 70x70, 5x5=25 windows,
// Bp=200 windows, 2400 (window,head) pairs. All GEMMs bf16 MFMA 16x16x32,
// fp32 accumulate. Softmax/LN/gelu in fp32.
// R3: GEMM = 128x128 tile, BK=32, explicit LDS double-buffer (32 KiB -> 3-4
// blocks/CU), global_load_lds staging issued BEFORE compute, single counted
// vmcnt(0) AFTER compute + raw s_barrier (T3-minimum 2-phase recipe), XOR
// bank swizzle (2-way, free), XCD-chunked bijective block swizzle.
// ---------------------------------------------------------------------------

typedef __bf16 bf16x8 __attribute__((ext_vector_type(8)));
typedef float f32x4 __attribute__((ext_vector_type(4)));
typedef unsigned int u32x4 __attribute__((ext_vector_type(4)));

__device__ __forceinline__ unsigned short f2bf(float f) {
  unsigned int u = __builtin_bit_cast(unsigned int, f);
  u += 0x7FFFu + ((u >> 16) & 1u);
  return (unsigned short)(u >> 16);
}

__device__ __forceinline__ bf16x8 ld8(const unsigned short* p) {
  return __builtin_bit_cast(bf16x8, *(const u32x4*)p);
}

// async global->LDS, 16B per lane. LDS dest must be wave-uniform base + lane*16.
__device__ __forceinline__ void gload_lds16(const unsigned short* g,
                                            unsigned short* l) {
  __builtin_amdgcn_global_load_lds(
      (const __attribute__((address_space(1))) unsigned int*)g,
      (__attribute__((address_space(3))) unsigned int*)l, 16, 0, 0);
}

// ---------------------------------------------------------------------------
// Weight transpose fp32[K][N] -> bf16[N][K]  (all dims multiples of 32)
// ---------------------------------------------------------------------------
__global__ void transpose_w(const float* __restrict__ in,
                            unsigned short* __restrict__ out, int K, int N) {
  __shared__ float t[32][33];
  int n = blockIdx.x * 32 + threadIdx.x;
  int kb = blockIdx.y * 32;
#pragma unroll
  for (int i = 0; i < 4; i++) {
    int k = kb + threadIdx.y + i * 8;
    t[threadIdx.y + i * 8][threadIdx.x] = in[(size_t)k * N + n];
  }
  __syncthreads();
  int k2 = kb + threadIdx.x;
#pragma unroll
  for (int i = 0; i < 4; i++) {
    int n2 = blockIdx.x * 32 + threadIdx.y + i * 8;
    out[(size_t)n2 * K + k2] = f2bf(t[threadIdx.x][threadIdx.y + i * 8]);
  }
}

// ---------------------------------------------------------------------------
// Rel-pos tables: Sh[i*14+j] = sum_c rel_h[(i-j+13)*64+c]; same for Sw.
// out layout: [0..195]=Sh, [196..391]=Sw
// ---------------------------------------------------------------------------
__global__ void shsw_kernel(const float* __restrict__ rh,
                            const float* __restrict__ rw,
                            float* __restrict__ o) {
  int t = threadIdx.x;
  if (t < 196) {
    int i = t / 14, j = t % 14, d = i - j + 13;
    float sh = 0.f, sw = 0.f;
    for (int c = 0; c < 64; c++) {
      sh += rh[d * 64 + c];
      sw += rw[d * 64 + c];
    }
    o[t] = sh;
    o[196 + t] = sw;
  }
}

// ---------------------------------------------------------------------------
// LayerNorm over 768. windowed=1: write to window-partitioned layout
// [win*196+t][768]; windowed=0: write [row][768]. Output bf16.
// ---------------------------------------------------------------------------
__global__ __launch_bounds__(256) void ln_kernel(
    const float* __restrict__ xin, const float* __restrict__ w,
    const float* __restrict__ b, unsigned short* __restrict__ out,
    int windowed) {
  __shared__ float red[8];
  __shared__ float ms[2];
  const int tid = threadIdx.x;
  const int blk = blockIdx.x;
  const float* xr = xin + (size_t)blk * 768;
  float v0 = xr[tid], v1 = xr[tid + 256], v2 = xr[tid + 512];
  float s = v0 + v1 + v2;
  float q = v0 * v0 + v1 * v1 + v2 * v2;
#pragma unroll
  for (int off = 32; off > 0; off >>= 1) {
    s += __shfl_down(s, off, 64);
    q += __shfl_down(q, off, 64);
  }
  const int wv = tid >> 6, lane = tid & 63;
  if (lane == 0) { red[wv] = s; red[4 + wv] = q; }
  __syncthreads();
  if (tid == 0) {
    float st = red[0] + red[1] + red[2] + red[3];
    float qt = red[4] + red[5] + red[6] + red[7];
    float mu = st * (1.0f / 768.0f);
    float var = qt * (1.0f / 768.0f) - mu * mu;
    ms[0] = mu;
    ms[1] = rsqrtf(var + 1e-5f);
  }
  __syncthreads();
  float mu = ms[0], sc = ms[1];
  unsigned short* dst;
  if (windowed) {
    int bb = blk >> 12, rem = blk & 4095, h = rem >> 6, ww = rem & 63;
    int win = (bb * 5 + h / 14) * 5 + ww / 14;
    int t = (h % 14) * 14 + (ww % 14);
    dst = out + ((size_t)win * 196 + t) * 768;
  } else {
    dst = out + (size_t)blk * 768;
  }
  dst[tid] = f2bf((v0 - mu) * sc * w[tid] + b[tid]);
  dst[tid + 256] = f2bf((v1 - mu) * sc * w[tid + 256] + b[tid + 256]);
  dst[tid + 512] = f2bf((v2 - mu) * sc * w[tid + 512] + b[tid + 512]);
}

// ---------------------------------------------------------------------------
// bf16 GEMM: C[M][N] = A[M][K] @ Bt[N][K]^T (+ epilogue)
// 128x128 block tile, BK=32, 4 waves in 2x2, each wave 64x64 (4x4 MFMA tiles).
// Explicit LDS double-buffer (2 x 16KB): per tile, STAGE(next) is issued
// FIRST (global_load_lds DMA), then ds_read+MFMA on current buffer, then one
// s_waitcnt vmcnt(0) + s_barrier -- the DMA latency hides under the tile's
// compute (T3-minimum 2-phase). 32KB LDS keeps 3-4 blocks/CU for TLP.
// LDS tile layout [128 rows][4 chunks of 16B], swizzled:
//   slot = chunk ^ (row&3) ^ (((row>>2)&1)<<1)
// -> ds_read_b128 per 16-lane group hits each (bank-half, slot) <=2x (free).
// DMA dest stays linear (tid*16B); the global SOURCE is inverse-permuted.
// EPI: 0=+bias->bf16 (qkv), 1=+bias+resid, window-unpartition ->fp32 d_out
//      2=+bias,gelu->bf16 (mlp1), 3=+bias, d_out += (mlp2)
// ---------------------------------------------------------------------------
template <int EPI>
__global__ __launch_bounds__(256, 2) void gemm_bt(
    const unsigned short* __restrict__ A, const unsigned short* __restrict__ Bt,
    const float* __restrict__ bias, int M, int N, int K,
    unsigned short* __restrict__ obf, float* __restrict__ of,
    const float* __restrict__ resid) {
  __shared__ __align__(16) unsigned short smem[2][8192];  // [buf][A:0..4096|B:4096..8192]
  const int tid = threadIdx.x;
  const int lane = tid & 63, wv = tid >> 6;
  const int ln15 = lane & 15, quad = lane >> 4;
  const int wm = wv & 1, wn = wv >> 1;

  // bijective XCD-chunked swizzle (8 XCDs)
  int bid = blockIdx.y * gridDim.x + blockIdx.x;
  {
    const int nwg = gridDim.x * gridDim.y;
    const int qq = nwg >> 3, rr = nwg & 7;
    const int xcd = bid & 7, lo = bid >> 3;
    bid = (xcd < rr ? xcd * (qq + 1) : rr * (qq + 1) + (xcd - rr) * qq) + lo;
  }
  const int m0 = (bid / gridDim.x) * 128, n0 = (bid % gridDim.x) * 128;

  // staging: thread t covers (row = q*64 + t>>2, slot = t&3) for q=0,1 in each
  // of A,B. LDS linear index = q*2048 + t*8 (wave-uniform base + lane*16B).
  // Source chunk for slot s of row r is s ^ (r&3) ^ (((r>>2)&1)<<1); with
  // r = q*64 + (t>>2) this is constant per thread:
  const int rr_ = tid >> 2;
  const int csrc =
      (((tid & 3) ^ ((tid >> 2) & 3) ^ (((tid >> 4) & 1) << 1)) << 3);
  const unsigned short* pA0 = A + (size_t)min(m0 + rr_, M - 1) * K + csrc;
  const unsigned short* pA1 = A + (size_t)min(m0 + 64 + rr_, M - 1) * K + csrc;
  const unsigned short* pB0 = Bt + (size_t)(n0 + rr_) * K + csrc;
  const unsigned short* pB1 = Bt + (size_t)(n0 + 64 + rr_) * K + csrc;

  // ds_read: lane (ln15,quad) wants global chunk=quad of row (..+ln15):
  const int rslot =
      ((quad ^ (ln15 & 3) ^ (((ln15 >> 2) & 1) << 1)) << 3);

  const f32x4 fz = {0.f, 0.f, 0.f, 0.f};
  f32x4 acc[4][4];
#pragma unroll
  for (int i = 0; i < 4; i++)
#pragma unroll
    for (int j = 0; j < 4; j++) acc[i][j] = fz;

#define STAGE(BUF, KT)                                                        \
  do {                                                                        \
    unsigned short* d_ = &smem[BUF][0] + tid * 8;                             \
    gload_lds16(pA0 + (KT), d_);                                              \
    gload_lds16(pA1 + (KT), d_ + 2048);                                       \
    gload_lds16(pB0 + (KT), d_ + 4096);                                       \
    gload_lds16(pB1 + (KT), d_ + 6144);                                       \
  } while (0)

  // prologue: stage tile 0, drain, barrier
  STAGE(0, 0);
  asm volatile("s_waitcnt vmcnt(0)" ::: "memory");
  __builtin_amdgcn_sched_barrier(0);
  __builtin_amdgcn_s_barrier();

  int cur = 0;
  for (int kt = 0; kt < K; kt += 32) {
    const bool more = (kt + 32 < K);
    if (more) STAGE(cur ^ 1, kt + 32);  // issue next-tile DMA before compute
    bf16x8 af[4], bv[4];
    const unsigned short* cb = &smem[cur][0];
#pragma unroll
    for (int t = 0; t < 4; t++) {
      af[t] = ld8(cb + (wm * 64 + t * 16 + ln15) * 32 + rslot);
      bv[t] = ld8(cb + 4096 + (wn * 64 + t * 16 + ln15) * 32 + rslot);
    }
#pragma unroll
    for (int i = 0; i < 4; i++)
#pragma unroll
      for (int j = 0; j < 4; j++)
        acc[i][j] =
            __builtin_amdgcn_mfma_f32_16x16x32_bf16(af[i], bv[j], acc[i][j], 0, 0, 0);
    if (more) {
      asm volatile("s_waitcnt vmcnt(0)" ::: "memory");  // next tile landed
      __builtin_amdgcn_sched_barrier(0);
      __builtin_amdgcn_s_barrier();
    }
    cur ^= 1;
  }
#undef STAGE

  // Epilogue. C/D layout: col = lane&15, row = quad*4 + reg (verified m89/m91).
#pragma unroll
  for (int i = 0; i < 4; i++) {
#pragma unroll
    for (int j = 0; j < 4; j++) {
      const int col = n0 + wn * 64 + j * 16 + ln15;
      const float bc = bias[col];
#pragma unroll
      for (int g = 0; g < 4; g++) {
        const int row = m0 + wm * 64 + i * 16 + quad * 4 + g;
        if (row >= M) continue;
        float v = acc[i][j][g] + bc;
        if constexpr (EPI == 0) {
          obf[(size_t)row * N + col] = f2bf(v);
        } else if constexpr (EPI == 2) {
          float gl = 0.5f * v * (1.0f + erff(v * 0.70710678118f));
          obf[(size_t)row * N + col] = f2bf(gl);
        } else if constexpr (EPI == 1) {
          // row -> (b,h,w) via window unpartition; drop padded positions
          int win = row / 196, t = row - win * 196;
          int b = win / 25, wg = win - b * 25;
          int wr = wg / 5, wc = wg - wr * 5;
          int h = wr * 14 + t / 14;
          int w = wc * 14 + (t % 14);
          if (h < 64 && w < 64) {
            size_t oi = (((size_t)(b * 64 + h)) * 64 + w) * 768 + col;
            of[oi] = v + resid[oi];
          }
        } else {  // EPI == 3
          size_t oi = (size_t)row * N + col;
          of[oi] += v;
        }
      }
    }
  }
}

// ---------------------------------------------------------------------------
// Fused windowed attention: one block per (window, head). 2400 blocks.
// qkv: bf16 [200*196][2304]; q cols h*64.., k cols 768+h*64.., v 1536+h*64..
// S = (Q Kt)*0.125 + Sh[qr,kr] + Sw[qc,kc]; softmax; O = P V.
// Q/K fragments read directly from global (L1-resident); V transposed in LDS;
// P strip round-trips LDS per wave (C-layout -> A-layout).
// ---------------------------------------------------------------------------
__global__ __launch_bounds__(256, 2) void attn_kernel(
    const unsigned short* __restrict__ qkv, const int* __restrict__ q_idx,
    const int* __restrict__ k_idx, const float* __restrict__ shsw,
    unsigned short* __restrict__ attnout) {
  __shared__ __align__(16) unsigned short Vt[64][232];   // [channel][key] pad->2-way banks
  __shared__ __align__(16) unsigned short Pst[4][16 * 232];  // per-wave P strip
  __shared__ float Shs[196], Sws[196];
  __shared__ short qr14a[208], qc14a[208], kra[208], kca[208];

  const int tid = threadIdx.x;
  const int blk = blockIdx.x;
  const int win = blk / 12, head = blk % 12;
  const int lane = tid & 63, wv = tid >> 6;
  const int ln15 = lane & 15, quad = lane >> 4;
  const unsigned short* qg = qkv + (size_t)win * 196 * 2304;

  // zero Vt & Pst (covers key/col padding 196..223 and strip cols 208..223)
  {
    unsigned int* vz = (unsigned int*)&Vt[0][0];
    for (int i = tid; i < 64 * 232 / 2; i += 256) vz[i] = 0u;
    unsigned int* pz = (unsigned int*)&Pst[0][0];
    for (int i = tid; i < 4 * 16 * 232 / 2; i += 256) pz[i] = 0u;
  }
  // V -> Vt transposed
  for (int i = tid; i < 196 * 64; i += 256) {
    int r = i >> 6, c = i & 63;
    Vt[c][r] = qg[(size_t)r * 2304 + 1536 + head * 64 + c];
  }
  // bias tables + index arrays
  for (int i = tid; i < 208; i += 256) {
    if (i < 196) {
      Shs[i] = shsw[i];
      Sws[i] = shsw[196 + i];
    }
    int q = (i < 196) ? q_idx[(size_t)blk * 196 + i] : 0;
    int k = (i < 196) ? k_idx[(size_t)blk * 196 + i] : 0;
    qr14a[i] = (short)((q / 14) * 14);
    qc14a[i] = (short)((q % 14) * 14);
    kra[i] = (short)(k / 14);
    kca[i] = (short)(k % 14);
  }
  __syncthreads();

  const f32x4 fz = {0.f, 0.f, 0.f, 0.f};
  unsigned short* strip = &Pst[wv][0];

  for (int mt = wv; mt < 13; mt += 4) {
    // ---- Q fragments (A-layout: m=lane&15, k=quad*8+j) from global ----
    int qrow = mt * 16 + ln15;
    int qrc = (qrow < 196) ? qrow : 0;
    const unsigned short* qrp = qg + (size_t)qrc * 2304 + head * 64 + quad * 8;
    bf16x8 aq0 = ld8(qrp);
    bf16x8 aq1 = ld8(qrp + 32);

    // ---- S = Q K^T over 13 col tiles ----
    f32x4 sacc[13];
#pragma unroll
    for (int nt = 0; nt < 13; nt++) {
      sacc[nt] = fz;
      int krow = nt * 16 + ln15;
      if (krow > 195) krow = 0;
      const unsigned short* krp =
          qg + (size_t)krow * 2304 + 768 + head * 64 + quad * 8;
      bf16x8 bk0 = ld8(krp);
      bf16x8 bk1 = ld8(krp + 32);
      sacc[nt] = __builtin_amdgcn_mfma_f32_16x16x32_bf16(aq0, bk0, sacc[nt], 0, 0, 0);
      sacc[nt] = __builtin_amdgcn_mfma_f32_16x16x32_bf16(aq1, bk1, sacc[nt], 0, 0, 0);
    }

    // ---- softmax (rows = quad*4+g of this mt tile) ----
    const int r0 = mt * 16 + quad * 4;
    int qi[4], qci[4];
#pragma unroll
    for (int g = 0; g < 4; g++) {
      qi[g] = qr14a[r0 + g];
      qci[g] = qc14a[r0 + g];
    }
    float rmax[4] = {-1e30f, -1e30f, -1e30f, -1e30f};
#pragma unroll
    for (int nt = 0; nt < 13; nt++) {
      int col = nt * 16 + ln15;
      int kr_ = kra[col], kc_ = kca[col];
#pragma unroll
      for (int g = 0; g < 4; g++) {
        float v = sacc[nt][g] * 0.125f + Shs[qi[g] + kr_] + Sws[qci[g] + kc_];
        if (col >= 196) v = -1e30f;
        sacc[nt][g] = v;
        rmax[g] = fmaxf(rmax[g], v);
      }
    }
#pragma unroll
    for (int off = 1; off < 16; off <<= 1)
#pragma unroll
      for (int g = 0; g < 4; g++)
        rmax[g] = fmaxf(rmax[g], __shfl_xor(rmax[g], off, 16));
    float rsum[4] = {0.f, 0.f, 0.f, 0.f};
#pragma unroll
    for (int nt = 0; nt < 13; nt++) {
      int col = nt * 16 + ln15;
#pragma unroll
      for (int g = 0; g < 4; g++) {
        float p = (col >= 196) ? 0.f : __expf(sacc[nt][g] - rmax[g]);
        sacc[nt][g] = p;
        rsum[g] += p;
      }
    }
#pragma unroll
    for (int off = 1; off < 16; off <<= 1)
#pragma unroll
      for (int g = 0; g < 4; g++) rsum[g] += __shfl_xor(rsum[g], off, 16);
    float rinv[4];
#pragma unroll
    for (int g = 0; g < 4; g++) rinv[g] = 1.0f / rsum[g];

    // ---- write P strip (row-major [16][232] bf16, A-layout source for PV) ----
#pragma unroll
    for (int nt = 0; nt < 13; nt++) {
      int col = nt * 16 + ln15;
#pragma unroll
      for (int g = 0; g < 4; g++)
        strip[(quad * 4 + g) * 232 + col] = f2bf(sacc[nt][g] * rinv[g]);
    }

    // ---- O = P V  (K padded to 224; strip/Vt zeros beyond 196) ----
    f32x4 oacc[4];
#pragma unroll
    for (int c4 = 0; c4 < 4; c4++) oacc[c4] = fz;
#pragma unroll
    for (int ks = 0; ks < 7; ks++) {
      bf16x8 ap = ld8(strip + ln15 * 232 + ks * 32 + quad * 8);
#pragma unroll
      for (int c4 = 0; c4 < 4; c4++) {
        bf16x8 bvv = ld8(&Vt[c4 * 16 + ln15][ks * 32 + quad * 8]);
        oacc[c4] = __builtin_amdgcn_mfma_f32_16x16x32_bf16(ap, bvv, oacc[c4], 0, 0, 0);
      }
    }
    // ---- store (C-layout: col=lane&15 channel, row=quad*4+g token) ----
#pragma unroll
    for (int c4 = 0; c4 < 4; c4++)
#pragma unroll
      for (int g = 0; g < 4; g++) {
        int row = r0 + g;
        if (row < 196)
          attnout[((size_t)win * 196 + row) * 768 + head * 64 + c4 * 16 + ln15] =
              f2bf(oacc[c4][g]);
      }
  }
}

// ---------------------------------------------------------------------------
// Launch. Workspace layout (bytes):
//   [0, 60211200)              region A: xw bf16 [39200][768] -> attnout -> ln2
//   [60211200, 261537792)      region B: qkv bf16 [39200][2304] -> mlp1 [32768][3072]
//   [261537792, ...)           transposed weights bf16 + ShSw tables (~14.2 MB)
// Peak ws use ~276 MB.
// ---------------------------------------------------------------------------
extern "C" void kernel_launch(void* const* d_in, const int* in_sizes, int n_in,
                              void* d_out, int out_size, void* d_ws,
                              size_t ws_size, hipStream_t stream) {
  const float* x = (const float*)d_in[0];
  const int* q_idx = (const int*)d_in[1];
  const int* k_idx = (const int*)d_in[2];
  const float* ln1w = (const float*)d_in[3];
  const float* ln1b = (const float*)d_in[4];
  const float* ln2w = (const float*)d_in[5];
  const float* ln2b = (const float*)d_in[6];
  const float* qkvw = (const float*)d_in[7];
  const float* qkvb = (const float*)d_in[8];
  const float* projw = (const float*)d_in[9];
  const float* projb = (const float*)d_in[10];
  const float* relh = (const float*)d_in[11];
  const float* relw = (const float*)d_in[12];
  const float* w1 = (const float*)d_in[13];
  const float* b1 = (const float*)d_in[14];
  const float* w2 = (const float*)d_in[15];
  const float* b2 = (const float*)d_in[16];
  float* out = (float*)d_out;

  char* ws = (char*)d_ws;
  unsigned short* xw = (unsigned short*)ws;  // region A
  const size_t offA = 60211200;              // 39200*768*2
  unsigned short* qkv = (unsigned short*)(ws + offA);  // region B
  const size_t offB = offA + 201326592;      // max(qkv, mlp1)
  unsigned short* qkvwt = (unsigned short*)(ws + offB);
  unsigned short* projwt = qkvwt + 2304 * 768;
  unsigned short* w1t = projwt + 768 * 768;
  unsigned short* w2t = w1t + 3072 * 768;
  float* shsw = (float*)(w2t + 768 * 3072);

  unsigned short* attnout = xw;  // region A reuse (xw dead after qkv GEMM)
  unsigned short* ln2buf = xw;   // region A reuse (attnout dead after proj)
  unsigned short* mlp1 = qkv;    // region B reuse (qkv dead after attention)

  // zero xw so spatially-padded window tokens are zero feature vectors
  hipMemsetAsync(xw, 0, (size_t)39200 * 768 * 2, stream);

  dim3 tb(32, 8);
  transpose_w<<<dim3(2304 / 32, 768 / 32), tb, 0, stream>>>(qkvw, qkvwt, 768, 2304);
  transpose_w<<<dim3(768 / 32, 768 / 32), tb, 0, stream>>>(projw, projwt, 768, 768);
  transpose_w<<<dim3(3072 / 32, 768 / 32), tb, 0, stream>>>(w1, w1t, 768, 3072);
  transpose_w<<<dim3(768 / 32, 3072 / 32), tb, 0, stream>>>(w2, w2t, 3072, 768);
  shsw_kernel<<<1, 256, 0, stream>>>(relh, relw, shsw);

  // LN1 + window partition -> bf16
  ln_kernel<<<32768, 256, 0, stream>>>(x, ln1w, ln1b, xw, 1);

  // qkv = xw @ qkv_w + b   [39200,768]x[768,2304]
  gemm_bt<0><<<dim3(18, 307), 256, 0, stream>>>(xw, qkvwt, qkvb, 39200, 2304,
                                                768, qkv, nullptr, nullptr);
  // fused windowed attention
  attn_kernel<<<2400, 256, 0, stream>>>(qkv, q_idx, k_idx, shsw, attnout);

  // proj + residual + unpartition -> d_out (fp32 x_mid)
  gemm_bt<1><<<dim3(6, 307), 256, 0, stream>>>(attnout, projwt, projb, 39200,
                                               768, 768, nullptr, out, x);
  // LN2 -> bf16
  ln_kernel<<<32768, 256, 0, stream>>>(out, ln2w, ln2b, ln2buf, 0);

  // mlp1 = gelu(ln2 @ w1 + b1)   [32768,768]x[768,3072]
  gemm_bt<2><<<dim3(24, 256), 256, 0, stream>>>(ln2buf, w1t, b1, 32768, 3072,
                                                768, mlp1, nullptr, nullptr);
  // d_out += mlp1 @ w2 + b2      [32768,3072]x[3072,768]
  gemm_bt<3><<<dim3(6, 256), 256, 0, stream>>>(mlp1, w2t, b2, 32768, 768, 3072,
                                               nullptr, out, nullptr);
  (void)in_sizes; (void)n_in; (void)out_size; (void)ws_size;
}